// Round 1
// baseline (521.801 us; speedup 1.0000x reference)
//
#include <hip/hip_runtime.h>
#include <hip/hip_bf16.h>

// Problem shapes (fixed for this dataset)
#define Bb 4
#define Nn 16
#define Ll 2048
#define Dd 512

// ---------------------------------------------------------------------------
// fp32 GEMM: C[M x 512] = A[M x 512] @ B[512 x 512] (+bias)
//   BT=false: B[k][n] = Bm[k*512 + n]   (row-major)
//   BT=true : B[k][n] = Bm[n*512 + k]   (transposed access, i.e. A @ Bm^T)
// 128x128 tile, 256 threads, 8x8 microtile, BK=16.
// ---------------------------------------------------------------------------
template <bool BT, bool BIAS>
__global__ __launch_bounds__(256) void gemm_f32(const float* __restrict__ A,
                                                const float* __restrict__ Bm,
                                                const float* __restrict__ bias,
                                                float* __restrict__ C) {
    const int K = 512;
    __shared__ float As[16][128];  // [k][m]
    __shared__ float Bs[16][128];  // [k][n]
    const int m0 = blockIdx.x * 128;
    const int n0 = blockIdx.y * 128;
    const int tid = threadIdx.x;
    const int tr = tid >> 4;   // 0..15
    const int tc = tid & 15;   // 0..15

    float acc[8][8];
#pragma unroll
    for (int i = 0; i < 8; i++)
#pragma unroll
        for (int j = 0; j < 8; j++) acc[i][j] = 0.f;

    for (int k0 = 0; k0 < K; k0 += 16) {
        // A tile: 128 rows x 16 cols; 512 float4s, 2 per thread; store transposed
#pragma unroll
        for (int i = 0; i < 2; i++) {
            int f = tid + i * 256;          // 0..511
            int row = f >> 2;               // 0..127
            int c4 = (f & 3) * 4;           // 0,4,8,12
            float4 v = *(const float4*)&A[(size_t)(m0 + row) * K + k0 + c4];
            As[c4 + 0][row] = v.x;
            As[c4 + 1][row] = v.y;
            As[c4 + 2][row] = v.z;
            As[c4 + 3][row] = v.w;
        }
        if (!BT) {
#pragma unroll
            for (int i = 0; i < 2; i++) {
                int f = tid + i * 256;
                int row = f >> 5;            // 0..15 (k)
                int c4 = (f & 31) * 4;       // 0..124 (n)
                float4 v = *(const float4*)&Bm[(size_t)(k0 + row) * 512 + n0 + c4];
                *(float4*)&Bs[row][c4] = v;
            }
        } else {
#pragma unroll
            for (int i = 0; i < 2; i++) {
                int f = tid + i * 256;
                int row = f >> 2;            // 0..127 (n)
                int c4 = (f & 3) * 4;        // 0,4,8,12 (k)
                float4 v = *(const float4*)&Bm[(size_t)(n0 + row) * 512 + k0 + c4];
                Bs[c4 + 0][row] = v.x;
                Bs[c4 + 1][row] = v.y;
                Bs[c4 + 2][row] = v.z;
                Bs[c4 + 3][row] = v.w;
            }
        }
        __syncthreads();
#pragma unroll
        for (int k = 0; k < 16; k++) {
            float a[8], bb[8];
            *(float4*)&a[0] = *(const float4*)&As[k][tr * 8];
            *(float4*)&a[4] = *(const float4*)&As[k][tr * 8 + 4];
            *(float4*)&bb[0] = *(const float4*)&Bs[k][tc * 8];
            *(float4*)&bb[4] = *(const float4*)&Bs[k][tc * 8 + 4];
#pragma unroll
            for (int i = 0; i < 8; i++)
#pragma unroll
                for (int j = 0; j < 8; j++) acc[i][j] += a[i] * bb[j];
        }
        __syncthreads();
    }

#pragma unroll
    for (int i = 0; i < 8; i++) {
        int row = m0 + tr * 8 + i;
#pragma unroll
        for (int j = 0; j < 8; j += 4) {
            int col = n0 + tc * 8 + j;
            float4 v = {acc[i][j], acc[i][j + 1], acc[i][j + 2], acc[i][j + 3]};
            if (BIAS) {
                v.x += bias[col + 0];
                v.y += bias[col + 1];
                v.z += bias[col + 2];
                v.w += bias[col + 3];
            }
            *(float4*)&C[(size_t)row * 512 + col] = v;
        }
    }
}

// ---------------------------------------------------------------------------
// Fused scores -> softmax -> pooling.
// One block per (b,l). Stages x[b,:,l,:] (16x512 f32 = 32KB) in LDS,
// computes 16 dots vs r[b,l,:], softmax over N=16, weighted sum.
// Reads x exactly once.
// ---------------------------------------------------------------------------
__global__ __launch_bounds__(256) void pool_kernel(const float* __restrict__ x,
                                                   const float* __restrict__ r,
                                                   float* __restrict__ out) {
    __shared__ float xs[Nn][Dd];
    __shared__ float s_s[Nn];
    const int row = blockIdx.x;  // b*L + l
    const int b = row >> 11;     // / 2048
    const int l = row & (Ll - 1);
    const int tid = threadIdx.x;
    const int wv = tid >> 6;
    const int lane = tid & 63;

    // r fragments for this lane (shared across the 4 n's this wave handles)
    const float4* rp = (const float4*)(r + (size_t)row * Dd);
    float4 rA = rp[lane];
    float4 rB = rp[lane + 64];

#pragma unroll
    for (int i = 0; i < 4; i++) {
        int n = wv * 4 + i;
        const float4* xp = (const float4*)(x + (((size_t)(b * Nn + n) * Ll) + l) * Dd);
        float4 v0 = xp[lane];
        float4 v1 = xp[lane + 64];
        *(float4*)&xs[n][lane * 4] = v0;
        *(float4*)&xs[n][256 + lane * 4] = v1;
        float acc = v0.x * rA.x + v0.y * rA.y + v0.z * rA.z + v0.w * rA.w +
                    v1.x * rB.x + v1.y * rB.y + v1.z * rB.z + v1.w * rB.w;
#pragma unroll
        for (int off = 32; off >= 1; off >>= 1) acc += __shfl_xor(acc, off);
        if (lane == 0) s_s[n] = acc * 0.04419417382415922f;  // 1/sqrt(512)
    }
    __syncthreads();

    // softmax over 16 (redundant per-thread; LDS broadcast reads)
    float w[Nn];
    float m = s_s[0];
#pragma unroll
    for (int n = 1; n < Nn; n++) m = fmaxf(m, s_s[n]);
    float sum = 0.f;
#pragma unroll
    for (int n = 0; n < Nn; n++) {
        w[n] = __expf(s_s[n] - m);
        sum += w[n];
    }
    const float inv = 1.0f / sum;

    float acc0 = 0.f, acc1 = 0.f;
#pragma unroll
    for (int n = 0; n < Nn; n++) {
        float wn = w[n] * inv;
        acc0 += wn * xs[n][tid];
        acc1 += wn * xs[n][tid + 256];
    }
    out[(size_t)row * Dd + tid] = acc0;
    out[(size_t)row * Dd + tid + 256] = acc1;
}

extern "C" void kernel_launch(void* const* d_in, const int* in_sizes, int n_in,
                              void* d_out, int out_size, void* d_ws, size_t ws_size,
                              hipStream_t stream) {
    const float* x = (const float*)d_in[0];        // (B,N,L,D)
    const float* highway = (const float*)d_in[1];  // (B,L,D)
    const float* Wq = (const float*)d_in[2];       // (D,D)
    const float* bq = (const float*)d_in[3];       // (D,)
    const float* Wk = (const float*)d_in[4];       // (D,D)
    // bk (d_in[5]) is provably irrelevant: its contribution to scores is
    // constant across n and softmax is shift-invariant.

    float* out = (float*)d_out;
    float* q = out;             // reuse d_out as q scratch (fully overwritten later)
    float* rbuf = (float*)d_ws; // 16 MB scratch for r

    const int M = Bb * Ll;  // 8192
    dim3 g1(M / 128, 512 / 128);

    // q = highway @ Wq^T + bq
    gemm_f32<true, true><<<g1, 256, 0, stream>>>(highway, Wq, bq, q);
    // r = q @ Wk
    gemm_f32<false, false><<<g1, 256, 0, stream>>>(q, Wk, nullptr, rbuf);
    // fused scores/softmax/pool
    pool_kernel<<<Bb * Ll, 256, 0, stream>>>(x, rbuf, out);
}

// Round 2
// 489.279 us; speedup vs baseline: 1.0665x; 1.0665x over previous
//
#include <hip/hip_runtime.h>
#include <hip/hip_bf16.h>

// Problem shapes (fixed for this dataset)
#define Bb 4
#define Nn 16
#define Ll 2048
#define Dd 512

// ---------------------------------------------------------------------------
// C[M x 512] = op(A) @ B (+ bias), op(A) = A (TRANS_A=0) or A^T (TRANS_A=1).
// A is [M x 512] (TRANS_A=0) or [512 x M] (TRANS_A=1); B is [512 x 512]
// row-major; bias indexed by column.
// 64x64 tile, BK=32, 256 threads, 4x4 microtile. Grid (M/64, 8).
// 64x64 tiles chosen over 128x128: grid 1024 blocks -> 4 blocks/CU (vs 1)
// for latency hiding; B re-reads are L2-resident (B is only 1 MB).
// ---------------------------------------------------------------------------
template <int TRANS_A, bool BIAS>
__global__ __launch_bounds__(256) void gemm64(const float* __restrict__ A,
                                              const float* __restrict__ Bm,
                                              const float* __restrict__ bias,
                                              float* __restrict__ C) {
    __shared__ __align__(16) float As[32][68];  // [k][m], +4 pad vs 64
    __shared__ __align__(16) float Bs[32][68];  // [k][n]
    const int m0 = blockIdx.x * 64;
    const int n0 = blockIdx.y * 64;
    const int tid = threadIdx.x;
    const int tr = tid >> 4;  // 0..15 -> rows m = tr*4..tr*4+3
    const int tc = tid & 15;  // 0..15 -> cols n = tc*4..tc*4+3

    float acc[4][4];
#pragma unroll
    for (int i = 0; i < 4; i++)
#pragma unroll
        for (int j = 0; j < 4; j++) acc[i][j] = 0.f;

    for (int k0 = 0; k0 < 512; k0 += 32) {
        if (TRANS_A) {
            // A is [512 x 512] accessed [k][m] — same pattern as B
#pragma unroll
            for (int it = 0; it < 2; it++) {
                int f = tid + it * 256;       // 0..511
                int kk = f >> 4;              // 0..31
                int c4 = (f & 15) * 4;        // 0..60
                float4 v = *(const float4*)&A[(size_t)(k0 + kk) * 512 + m0 + c4];
                *(float4*)&As[kk][c4] = v;
            }
        } else {
#pragma unroll
            for (int it = 0; it < 2; it++) {
                int f = tid + it * 256;       // 0..511
                int row = f >> 3;             // 0..63 (m)
                int c4 = (f & 7) * 4;         // 0..28 (k)
                float4 v = *(const float4*)&A[(size_t)(m0 + row) * 512 + k0 + c4];
                As[c4 + 0][row] = v.x;
                As[c4 + 1][row] = v.y;
                As[c4 + 2][row] = v.z;
                As[c4 + 3][row] = v.w;
            }
        }
#pragma unroll
        for (int it = 0; it < 2; it++) {
            int f = tid + it * 256;
            int kk = f >> 4;
            int c4 = (f & 15) * 4;
            float4 v = *(const float4*)&Bm[(size_t)(k0 + kk) * 512 + n0 + c4];
            *(float4*)&Bs[kk][c4] = v;
        }
        __syncthreads();
#pragma unroll
        for (int k = 0; k < 32; k++) {
            float a[4], b[4];
            *(float4*)&a[0] = *(const float4*)&As[k][tr * 4];
            *(float4*)&b[0] = *(const float4*)&Bs[k][tc * 4];
#pragma unroll
            for (int i = 0; i < 4; i++)
#pragma unroll
                for (int j = 0; j < 4; j++) acc[i][j] += a[i] * b[j];
        }
        __syncthreads();
    }

#pragma unroll
    for (int i = 0; i < 4; i++) {
        int row = m0 + tr * 4 + i;
        int col = n0 + tc * 4;
        float4 v = {acc[i][0], acc[i][1], acc[i][2], acc[i][3]};
        if (BIAS) {
            v.x += bias[col + 0];
            v.y += bias[col + 1];
            v.z += bias[col + 2];
            v.w += bias[col + 3];
        }
        *(float4*)&C[(size_t)row * 512 + col] = v;
    }
}

// bc[j] = sum_k bq[k] * Wk[k][j]   (tiny; bq is uniform -> scalar loads)
__global__ __launch_bounds__(256) void bc_kernel(const float* __restrict__ bq,
                                                 const float* __restrict__ Wk,
                                                 float* __restrict__ bc) {
    int j = blockIdx.x * 256 + threadIdx.x;
    float acc = 0.f;
#pragma unroll 4
    for (int k = 0; k < 512; k++) acc += bq[k] * Wk[(size_t)k * 512 + j];
    bc[j] = acc;
}

// ---------------------------------------------------------------------------
// Fused scores -> softmax -> pooling. One block per (b,l); 4 waves, each wave
// owns 4 neurons. x rows stay in REGISTERS (xv[4][2] float4 per lane); only
// the 4 per-wave weighted partials (8 KB) go through LDS.
// ---------------------------------------------------------------------------
__global__ __launch_bounds__(256) void pool_kernel(const float* __restrict__ x,
                                                   const float* __restrict__ r,
                                                   float* __restrict__ out) {
    __shared__ __align__(16) float part[4][Dd];  // per-wave weighted partials
    __shared__ float s_s[Nn];
    const int row = blockIdx.x;  // b*L + l
    const int b = row >> 11;
    const int l = row & (Ll - 1);
    const int tid = threadIdx.x;
    const int wv = tid >> 6;
    const int lane = tid & 63;

    const float4* rp = (const float4*)(r + (size_t)row * Dd);
    float4 rA = rp[lane];
    float4 rB = rp[lane + 64];

    float4 xv0_0, xv0_1, xv1_0, xv1_1, xv2_0, xv2_1, xv3_0, xv3_1;
#define LOADDOT(I, VA, VB)                                                         \
    {                                                                              \
        int n = wv * 4 + I;                                                        \
        const float4* xp =                                                         \
            (const float4*)(x + (((size_t)(b * Nn + n) * Ll) + l) * Dd);           \
        VA = xp[lane];                                                             \
        VB = xp[lane + 64];                                                        \
        float acc = VA.x * rA.x + VA.y * rA.y + VA.z * rA.z + VA.w * rA.w +        \
                    VB.x * rB.x + VB.y * rB.y + VB.z * rB.z + VB.w * rB.w;         \
        _Pragma("unroll") for (int off = 32; off >= 1; off >>= 1) acc +=           \
            __shfl_xor(acc, off);                                                  \
        if (lane == 0) s_s[n] = acc * 0.04419417382415922f; /* 1/sqrt(512) */      \
    }
    LOADDOT(0, xv0_0, xv0_1)
    LOADDOT(1, xv1_0, xv1_1)
    LOADDOT(2, xv2_0, xv2_1)
    LOADDOT(3, xv3_0, xv3_1)
#undef LOADDOT
    __syncthreads();

    // softmax over N=16 (redundant per-thread; s_s reads are LDS broadcasts)
    float m = s_s[0];
#pragma unroll
    for (int n = 1; n < Nn; n++) m = fmaxf(m, s_s[n]);
    float sum = 0.f;
#pragma unroll
    for (int n = 0; n < Nn; n++) sum += __expf(s_s[n] - m);
    const float inv = 1.0f / sum;

    float4 p0 = {0.f, 0.f, 0.f, 0.f}, p1 = {0.f, 0.f, 0.f, 0.f};
#define ACCW(I, VA, VB)                                                            \
    {                                                                              \
        float wn = __expf(s_s[wv * 4 + I] - m) * inv;                              \
        p0.x += wn * VA.x; p0.y += wn * VA.y; p0.z += wn * VA.z; p0.w += wn * VA.w;\
        p1.x += wn * VB.x; p1.y += wn * VB.y; p1.z += wn * VB.z; p1.w += wn * VB.w;\
    }
    ACCW(0, xv0_0, xv0_1)
    ACCW(1, xv1_0, xv1_1)
    ACCW(2, xv2_0, xv2_1)
    ACCW(3, xv3_0, xv3_1)
#undef ACCW

    *(float4*)&part[wv][lane * 4] = p0;
    *(float4*)&part[wv][256 + lane * 4] = p1;
    __syncthreads();

    float2 o;
    o.x = part[0][2 * tid] + part[1][2 * tid] + part[2][2 * tid] + part[3][2 * tid];
    o.y = part[0][2 * tid + 1] + part[1][2 * tid + 1] + part[2][2 * tid + 1] +
          part[3][2 * tid + 1];
    *(float2*)&out[(size_t)row * Dd + 2 * tid] = o;
}

extern "C" void kernel_launch(void* const* d_in, const int* in_sizes, int n_in,
                              void* d_out, int out_size, void* d_ws, size_t ws_size,
                              hipStream_t stream) {
    const float* x = (const float*)d_in[0];        // (B,N,L,D)
    const float* highway = (const float*)d_in[1];  // (B,L,D)
    const float* Wq = (const float*)d_in[2];       // (D,D)
    const float* bq = (const float*)d_in[3];       // (D,)
    const float* Wk = (const float*)d_in[4];       // (D,D)
    // bk (d_in[5]) is irrelevant: its score contribution is constant across n
    // and softmax is shift-invariant.

    float* out = (float*)d_out;
    float* Wc = (float*)d_ws;            // 512*512 = 1 MB
    float* bc = Wc + 512 * 512;          // 512 floats
    float* rbuf = bc + 512;              // 8192*512 = 16 MB

    // Wc = Wq^T @ Wk  (r = q@Wk = H@Wc + bq@Wk, since q = H@Wq^T + bq)
    dim3 gw(8, 8);
    gemm64<1, false><<<gw, 256, 0, stream>>>(Wq, Wk, nullptr, Wc);
    // bc = bq @ Wk
    bc_kernel<<<2, 256, 0, stream>>>(bq, Wk, bc);
    // r = highway @ Wc + bc
    dim3 gr((Bb * Ll) / 64, 8);
    gemm64<0, true><<<gr, 256, 0, stream>>>(highway, Wc, bc, rbuf);
    // fused scores/softmax/pool
    pool_kernel<<<Bb * Ll, 256, 0, stream>>>(x, rbuf, out);
}

// Round 4
// 424.720 us; speedup vs baseline: 1.2286x; 1.1520x over previous
//
#include <hip/hip_runtime.h>
#include <hip/hip_bf16.h>

#define Bb 4
#define Nn 16
#define Ll 2048
#define Dd 512

typedef __attribute__((ext_vector_type(8))) short bf16x8;
typedef __attribute__((ext_vector_type(4))) float f32x4;

static __device__ __forceinline__ unsigned short f2bf(float f) {
    unsigned int u = __float_as_uint(f);
    unsigned int r = (u + 0x7fffu + ((u >> 16) & 1u)) >> 16;  // RTNE
    return (unsigned short)r;
}

// ---------------------------------------------------------------------------
// prep: WcT[e][d] = sum_k Wq[k][d] * Wk[k][e]  (bf16, pre-transposed for rgemm)
//       bc[e]    = sum_k bq[k]   * Wk[k][e]
// Grid (16,16): 32x32 Wc tile per block; K=512 split 4-way across waves
// (serial depth 128), LDS cross-wave reduce. bc by blockIdx.x==0 blocks.
// ---------------------------------------------------------------------------
__global__ __launch_bounds__(256) void prep_kernel(const float* __restrict__ Wq,
                                                   const float* __restrict__ Wk,
                                                   const float* __restrict__ bq,
                                                   unsigned short* __restrict__ WcT,
                                                   float* __restrict__ bc) {
    __shared__ float red[4][32][33];
    __shared__ float bcl[8][32];
    const int d0 = blockIdx.x * 32;
    const int e0 = blockIdx.y * 32;
    const int tid = threadIdx.x;
    const int w = tid >> 6, lane = tid & 63;
    const int lr = lane >> 3, lc = lane & 7;

    float acc[4][4];
#pragma unroll
    for (int i = 0; i < 4; i++)
#pragma unroll
        for (int j = 0; j < 4; j++) acc[i][j] = 0.f;

    const int kbeg = w * 128;
#pragma unroll 4
    for (int k = kbeg; k < kbeg + 128; k++) {
        float4 aq = *(const float4*)&Wq[(size_t)k * 512 + d0 + lr * 4];
        float4 ak = *(const float4*)&Wk[(size_t)k * 512 + e0 + lc * 4];
        float a4[4] = {aq.x, aq.y, aq.z, aq.w};
        float b4[4] = {ak.x, ak.y, ak.z, ak.w};
#pragma unroll
        for (int i = 0; i < 4; i++)
#pragma unroll
            for (int j = 0; j < 4; j++) acc[i][j] += a4[i] * b4[j];
    }
#pragma unroll
    for (int i = 0; i < 4; i++)
#pragma unroll
        for (int j = 0; j < 4; j++) red[w][lr * 4 + i][lc * 4 + j] = acc[i][j];

    if (blockIdx.x == 0) {  // bc partials
        const int n = tid & 31, kq = tid >> 5;
        float p = 0.f;
#pragma unroll 4
        for (int k = kq * 64; k < kq * 64 + 64; k++)
            p += bq[k] * Wk[(size_t)k * 512 + e0 + n];
        bcl[kq][n] = p;
    }
    __syncthreads();

    {
        const int n = tid >> 3;           // 0..31 (e-local)
        const int d4 = (tid & 7) * 4;     // 0..28 (d-local)
        unsigned int lo, hi;
        float v0 = red[0][d4 + 0][n] + red[1][d4 + 0][n] + red[2][d4 + 0][n] + red[3][d4 + 0][n];
        float v1 = red[0][d4 + 1][n] + red[1][d4 + 1][n] + red[2][d4 + 1][n] + red[3][d4 + 1][n];
        float v2 = red[0][d4 + 2][n] + red[1][d4 + 2][n] + red[2][d4 + 2][n] + red[3][d4 + 2][n];
        float v3 = red[0][d4 + 3][n] + red[1][d4 + 3][n] + red[2][d4 + 3][n] + red[3][d4 + 3][n];
        lo = (unsigned)f2bf(v0) | ((unsigned)f2bf(v1) << 16);
        hi = (unsigned)f2bf(v2) | ((unsigned)f2bf(v3) << 16);
        uint2 o = {lo, hi};
        *(uint2*)&WcT[(size_t)(e0 + n) * 512 + d0 + d4] = o;
    }
    if (blockIdx.x == 0 && tid < 32) {
        float s = 0.f;
#pragma unroll
        for (int q = 0; q < 8; q++) s += bcl[q][tid];
        bc[e0 + tid] = s;
    }
}

// ---------------------------------------------------------------------------
// rgemm: r[MxE] = H[MxD] @ Wc[DxE] + bc, bf16 MFMA 16x16x32, fp32 accum.
// 64x64 tile, BK=64, 4 waves (2x2, each 32x32 out). Grid 1024 (nb fast).
// A (H) converted f32->bf16 during staging; B from pre-transposed WcT.
// LDS rows padded to 72 bf16 (144 B) -> 2-way-max bank aliasing on b128.
// ---------------------------------------------------------------------------
__global__ __launch_bounds__(256) void rgemm_kernel(const float* __restrict__ H,
                                                    const unsigned short* __restrict__ WcT,
                                                    const float* __restrict__ bc,
                                                    float* __restrict__ r) {
    __shared__ unsigned short Asd[64][72];  // [m][k]
    __shared__ unsigned short Bsd[64][72];  // [e][k]
    const int bid = blockIdx.x;
    const int nb = bid & 7, mb = bid >> 3;
    const int m0 = mb * 64, e0 = nb * 64;
    const int tid = threadIdx.x;
    const int w = tid >> 6, lane = tid & 63;
    const int wr = w >> 1, wc = w & 1;

    f32x4 acc[2][2];
#pragma unroll
    for (int i = 0; i < 2; i++)
#pragma unroll
        for (int j = 0; j < 2; j++) acc[i][j] = (f32x4){0.f, 0.f, 0.f, 0.f};

    for (int k0 = 0; k0 < 512; k0 += 64) {
        // A stage: 64 rows x 64 k fp32 -> bf16
#pragma unroll
        for (int it = 0; it < 4; it++) {
            int f = tid + it * 256;        // 0..1023
            int m = f >> 4;                // 0..63
            int k4 = (f & 15) * 4;         // 0..60
            float4 v = *(const float4*)&H[(size_t)(m0 + m) * 512 + k0 + k4];
            uint2 o = {(unsigned)f2bf(v.x) | ((unsigned)f2bf(v.y) << 16),
                       (unsigned)f2bf(v.z) | ((unsigned)f2bf(v.w) << 16)};
            *(uint2*)&Asd[m][k4] = o;
        }
        // B stage: 64 rows x 64 k bf16 (16B chunks)
#pragma unroll
        for (int it = 0; it < 2; it++) {
            int f = tid + it * 256;        // 0..511
            int n = f >> 3;                // 0..63
            int k8 = (f & 7) * 8;          // 0..56
            uint4 v = *(const uint4*)&WcT[(size_t)(e0 + n) * 512 + k0 + k8];
            *(uint4*)&Bsd[n][k8] = v;
        }
        __syncthreads();
#pragma unroll
        for (int kc = 0; kc < 2; kc++) {
            const int ko = kc * 32 + (lane >> 4) * 8;
            bf16x8 a0 = *(const bf16x8*)&Asd[wr * 32 + (lane & 15)][ko];
            bf16x8 a1 = *(const bf16x8*)&Asd[wr * 32 + 16 + (lane & 15)][ko];
            bf16x8 b0 = *(const bf16x8*)&Bsd[wc * 32 + (lane & 15)][ko];
            bf16x8 b1 = *(const bf16x8*)&Bsd[wc * 32 + 16 + (lane & 15)][ko];
            acc[0][0] = __builtin_amdgcn_mfma_f32_16x16x32_bf16(a0, b0, acc[0][0], 0, 0, 0);
            acc[0][1] = __builtin_amdgcn_mfma_f32_16x16x32_bf16(a0, b1, acc[0][1], 0, 0, 0);
            acc[1][0] = __builtin_amdgcn_mfma_f32_16x16x32_bf16(a1, b0, acc[1][0], 0, 0, 0);
            acc[1][1] = __builtin_amdgcn_mfma_f32_16x16x32_bf16(a1, b1, acc[1][1], 0, 0, 0);
        }
        __syncthreads();
    }
    // epilogue: C row = (lane>>4)*4+j, col = lane&15 (m89-verified layout)
    const int colbase = e0 + wc * 32 + (lane & 15);
    const int rowbase = m0 + wr * 32 + (lane >> 4) * 4;
#pragma unroll
    for (int nj = 0; nj < 2; nj++) {
        float bcv = bc[colbase + nj * 16];
#pragma unroll
        for (int mi = 0; mi < 2; mi++)
#pragma unroll
            for (int j = 0; j < 4; j++)
                r[(size_t)(rowbase + mi * 16 + j) * 512 + colbase + nj * 16] =
                    acc[mi][nj][j] + bcv;
    }
}

// ---------------------------------------------------------------------------
// Fused scores -> softmax -> pooling. One block per (b,l); 4 waves x 4 neurons.
// x rows stay in registers; r staged once in LDS (not 4x redundant loads).
// ---------------------------------------------------------------------------
__global__ __launch_bounds__(256) void pool_kernel(const float* __restrict__ x,
                                                   const float* __restrict__ r,
                                                   float* __restrict__ out) {
    __shared__ float4 rs[128];
    __shared__ float part[4][Dd];
    __shared__ float s_s[Nn];
    const int row = blockIdx.x;  // b*L + l
    const int b = row >> 11;
    const int l = row & (Ll - 1);
    const int tid = threadIdx.x;
    const int wv = tid >> 6;
    const int lane = tid & 63;

    // issue the 8 x-loads (4 neurons x 2 float4) before the r barrier
    const size_t nstride = (size_t)Ll * (Dd / 4);  // float4 per neuron plane
    const float4* xp = (const float4*)x + ((size_t)(b * Nn + wv * 4) * Ll + l) * (Dd / 4);
    float4 x00 = xp[lane], x01 = xp[lane + 64];
    xp += nstride;
    float4 x10 = xp[lane], x11 = xp[lane + 64];
    xp += nstride;
    float4 x20 = xp[lane], x21 = xp[lane + 64];
    xp += nstride;
    float4 x30 = xp[lane], x31 = xp[lane + 64];

    if (tid < 128) rs[tid] = ((const float4*)(r + (size_t)row * Dd))[tid];
    __syncthreads();
    const float4 rA = rs[lane];
    const float4 rB = rs[lane + 64];

#define DOT(I, VA, VB)                                                              \
    {                                                                               \
        float acc = VA.x * rA.x + VA.y * rA.y + VA.z * rA.z + VA.w * rA.w +         \
                    VB.x * rB.x + VB.y * rB.y + VB.z * rB.z + VB.w * rB.w;          \
        _Pragma("unroll") for (int off = 32; off >= 1; off >>= 1) acc +=            \
            __shfl_xor(acc, off);                                                   \
        if (lane == 0) s_s[wv * 4 + I] = acc * 0.04419417382415922f;                \
    }
    DOT(0, x00, x01)
    DOT(1, x10, x11)
    DOT(2, x20, x21)
    DOT(3, x30, x31)
#undef DOT
    __syncthreads();

    float m = s_s[0];
#pragma unroll
    for (int n = 1; n < Nn; n++) m = fmaxf(m, s_s[n]);
    float sum = 0.f;
#pragma unroll
    for (int n = 0; n < Nn; n++) sum += __expf(s_s[n] - m);
    const float inv = 1.0f / sum;

    float4 p0 = {0.f, 0.f, 0.f, 0.f}, p1 = {0.f, 0.f, 0.f, 0.f};
#define ACCW(I, VA, VB)                                                             \
    {                                                                               \
        float wn = __expf(s_s[wv * 4 + I] - m) * inv;                               \
        p0.x += wn * VA.x; p0.y += wn * VA.y; p0.z += wn * VA.z; p0.w += wn * VA.w; \
        p1.x += wn * VB.x; p1.y += wn * VB.y; p1.z += wn * VB.z; p1.w += wn * VB.w; \
    }
    ACCW(0, x00, x01)
    ACCW(1, x10, x11)
    ACCW(2, x20, x21)
    ACCW(3, x30, x31)
#undef ACCW

    *(float4*)&part[wv][lane * 4] = p0;
    *(float4*)&part[wv][256 + lane * 4] = p1;
    __syncthreads();

    float2 a0 = *(const float2*)&part[0][2 * tid];
    float2 a1 = *(const float2*)&part[1][2 * tid];
    float2 a2 = *(const float2*)&part[2][2 * tid];
    float2 a3 = *(const float2*)&part[3][2 * tid];
    float2 o = {a0.x + a1.x + a2.x + a3.x, a0.y + a1.y + a2.y + a3.y};
    *(float2*)&out[(size_t)row * Dd + 2 * tid] = o;
}

extern "C" void kernel_launch(void* const* d_in, const int* in_sizes, int n_in,
                              void* d_out, int out_size, void* d_ws, size_t ws_size,
                              hipStream_t stream) {
    const float* x = (const float*)d_in[0];        // (B,N,L,D)
    const float* highway = (const float*)d_in[1];  // (B,L,D)
    const float* Wq = (const float*)d_in[2];       // (D,D)
    const float* bq = (const float*)d_in[3];       // (D,)
    const float* Wk = (const float*)d_in[4];       // (D,D)
    // bk (d_in[5]) drops out: constant across n under softmax.

    float* out = (float*)d_out;
    unsigned short* WcT = (unsigned short*)d_ws;            // 512*512 bf16 = 512 KB
    float* bc = (float*)((char*)d_ws + 512 * 512 * 2);      // 2 KB
    float* rbuf = (float*)((char*)d_ws + 512 * 512 * 2 + 2048);  // 16 MB

    dim3 gp(16, 16);
    prep_kernel<<<gp, 256, 0, stream>>>(Wq, Wk, bq, WcT, bc);
    rgemm_kernel<<<(Bb * Ll / 64) * 8, 256, 0, stream>>>(highway, WcT, bc, rbuf);
    pool_kernel<<<Bb * Ll, 256, 0, stream>>>(x, rbuf, out);
}